// Round 1
// baseline (292.839 us; speedup 1.0000x reference)
//
#include <hip/hip_runtime.h>
#include <math.h>

#define N_MESH   5151
#define NB       8
#define TT       2048
#define HID      256
#define NLAYERS  3
#define INV_TEMP 1000.0f
#define NBLK_N   21            // ceil(5151/256)

// ws layout (floats)
#define WS_DENSITY 0           // 5151 used
#define WS_SUM     5184        // 1
#define WS_PART    6144        // NB * NBLK_N * TT = 344064

// out layout (floats)
#define OUT_BNORM  0           // 16384
#define OUT_DENSB  16384       // 41208
#define OUT_M      57592       // 16384
#define OUT_S0     73976       // 41208
#define OUT_MESHB  115184      // 82416

__device__ __forceinline__ float sigmoid_fast(float x) {
    // 1/(1+exp(-x)); saturates exactly for |x| large
    float e = __expf(-x);
    return __builtin_amdgcn_rcpf(1.0f + e);
}

// ---------------------------------------------------------------------------
// Density MLP: rows wave-private (row = rg + 4*j), zero barriers.
// block = 256 threads (4 waves), BM = 32 rows/block.
// ---------------------------------------------------------------------------
__global__ __launch_bounds__(256) void mlp_kernel(
    const float* __restrict__ mesh, const float* __restrict__ Win,
    const float* __restrict__ bin,  const float* __restrict__ Wblk,
    const float* __restrict__ bblk, const float* __restrict__ Wout,
    const float* __restrict__ bout, float* __restrict__ ws_density)
{
    __shared__ float hA[32 * HID];          // 32 KB
    const int tid = threadIdx.x;
    const int lane = tid & 63;              // col group
    const int rg   = tid >> 6;              // row group == wave id
    const int c0   = lane * 4;
    const int row0 = blockIdx.x * 32;

    // input layer: h0 = relu(mesh @ Win + bin)
    float4 w0 = *(const float4*)&Win[0 * HID + c0];
    float4 w1 = *(const float4*)&Win[1 * HID + c0];
    float4 bi = *(const float4*)&bin[c0];
#pragma unroll
    for (int j = 0; j < 8; ++j) {
        int r = rg + 4 * j;
        int gr = row0 + r;
        float m0 = 0.f, m1 = 0.f;
        if (gr < N_MESH) { m0 = mesh[2 * gr]; m1 = mesh[2 * gr + 1]; }
        float4 h;
        h.x = fmaxf(fmaf(m0, w0.x, fmaf(m1, w1.x, bi.x)), 0.f);
        h.y = fmaxf(fmaf(m0, w0.y, fmaf(m1, w1.y, bi.y)), 0.f);
        h.z = fmaxf(fmaf(m0, w0.z, fmaf(m1, w1.z, bi.z)), 0.f);
        h.w = fmaxf(fmaf(m0, w0.w, fmaf(m1, w1.w, bi.w)), 0.f);
        *(float4*)&hA[r * HID + c0] = h;
    }

    // 3 residual layers, in-place (rows are wave-private)
    for (int L = 0; L < NLAYERS; ++L) {
        const float* W = Wblk + (size_t)L * HID * HID;
        float acc[8][4];
#pragma unroll
        for (int j = 0; j < 8; ++j)
#pragma unroll
            for (int q = 0; q < 4; ++q) acc[j][q] = 0.f;

#pragma unroll 4
        for (int k = 0; k < HID; ++k) {
            float4 w = *(const float4*)&W[k * HID + c0];
#pragma unroll
            for (int j = 0; j < 8; ++j) {
                float hv = hA[(rg + 4 * j) * HID + k];   // wave-broadcast
                acc[j][0] = fmaf(hv, w.x, acc[j][0]);
                acc[j][1] = fmaf(hv, w.y, acc[j][1]);
                acc[j][2] = fmaf(hv, w.z, acc[j][2]);
                acc[j][3] = fmaf(hv, w.w, acc[j][3]);
            }
        }
        float4 bb = *(const float4*)&bblk[L * HID + c0];
#pragma unroll
        for (int j = 0; j < 8; ++j) {
            int r = rg + 4 * j;
            float4 h = *(float4*)&hA[r * HID + c0];
            h.x += fmaxf(acc[j][0] + bb.x, 0.f);
            h.y += fmaxf(acc[j][1] + bb.y, 0.f);
            h.z += fmaxf(acc[j][2] + bb.z, 0.f);
            h.w += fmaxf(acc[j][3] + bb.w, 0.f);
            *(float4*)&hA[r * HID + c0] = h;
        }
    }

    // output layer + sigmoid
    float4 wo = *(const float4*)&Wout[c0];
    float bo = bout[0];
    float p[8];
#pragma unroll
    for (int j = 0; j < 8; ++j) {
        int r = rg + 4 * j;
        float4 h = *(float4*)&hA[r * HID + c0];
        p[j] = h.x * wo.x + h.y * wo.y + h.z * wo.z + h.w * wo.w;
    }
#pragma unroll
    for (int st = 1; st < 64; st <<= 1)
#pragma unroll
        for (int j = 0; j < 8; ++j) p[j] += __shfl_xor(p[j], st, 64);

    if (lane < 8) {
        float sel = p[0];
#pragma unroll
        for (int j = 1; j < 8; ++j) if (lane == j) sel = p[j];
        int gr = row0 + rg + 4 * lane;
        if (gr < N_MESH) ws_density[gr] = sigmoid_fast(sel + bo);
    }
}

// ---------------------------------------------------------------------------
// Sum of density (single block, deterministic order)
// ---------------------------------------------------------------------------
__global__ __launch_bounds__(256) void sum_kernel(const float* __restrict__ density,
                                                  float* __restrict__ sum_out)
{
    __shared__ float red[4];
    float p = 0.f;
    for (int i = threadIdx.x; i < N_MESH; i += 256) p += density[i];
#pragma unroll
    for (int st = 1; st < 64; st <<= 1) p += __shfl_xor(p, st, 64);
    int lane = threadIdx.x & 63, w = threadIdx.x >> 6;
    if (lane == 0) red[w] = p;
    __syncthreads();
    if (threadIdx.x == 0) sum_out[0] = red[0] + red[1] + red[2] + red[3];
}

// ---------------------------------------------------------------------------
// Broadcast/copy outputs 1 (density_b), 3 (initial_states), 4 (mesh_b)
// ---------------------------------------------------------------------------
__global__ __launch_bounds__(256) void bcast_kernel(
    const float* __restrict__ density, const float* __restrict__ s0,
    const float* __restrict__ mesh, float* __restrict__ out)
{
    int i = blockIdx.x * blockDim.x + threadIdx.x;
    const int n1 = NB * N_MESH;            // 41208
    const int n2 = 2 * n1;                 // 82416
    const int total = n2 + NB * N_MESH * 2; // 164832
    if (i >= total) return;
    if (i < n1) {
        out[OUT_DENSB + i] = density[i % N_MESH];
    } else if (i < n2) {
        int j = i - n1;
        out[OUT_S0 + j] = s0[j];
    } else {
        int j = i - n2;
        out[OUT_MESHB + j] = mesh[j % (2 * N_MESH)];
    }
}

// ---------------------------------------------------------------------------
// Hysteresis scan: one state per thread, 2048 sequential steps,
// 16-step chunks with interleaved butterflies to hide shuffle latency.
// grid = (NBLK_N, NB), block = 256.
// ---------------------------------------------------------------------------
__global__ __launch_bounds__(256) void scan_kernel(
    const float* __restrict__ dec, const float* __restrict__ s0_in,
    const float* __restrict__ y0,  const float* __restrict__ mesh,
    const float* __restrict__ density, float* __restrict__ partials)
{
    __shared__ float hs[TT];               // 8 KB
    __shared__ float red[4][16];
    const int tid = threadIdx.x;
    const int b   = blockIdx.y;
    const int nb  = blockIdx.x;
    const int n   = nb * 256 + tid;
    const int lane = tid & 63;
    const int w    = tid >> 6;

    for (int t = tid; t < TT; t += 256) hs[t] = dec[b * TT + t];

    float s, d, alpha, beta;
    if (n < N_MESH) {
        s = s0_in[b * N_MESH + n];
        d = density[n];
        beta  = mesh[2 * n];
        alpha = mesh[2 * n + 1];
    } else { s = 0.f; d = 0.f; alpha = 4.f; beta = 4.f; }
    float hp = y0[b];
    __syncthreads();

    for (int tb = 0; tb < TT; tb += 16) {
        float v[16];
#pragma unroll
        for (int j = 0; j < 16; ++j) {
            float ht = hs[tb + j];
            bool inc = (ht >= hp);          // uniform within block
            hp = ht;
            float thr  = inc ? alpha : beta;
            float e    = __expf((thr - ht) * INV_TEMP);   // exp(-x)
            float sg   = __builtin_amdgcn_rcpf(1.0f + e); // sigmoid(x)
            float a    = inc ? (1.0f - s) : (s + 1.0f);
            float base = inc ? s : -1.0f;
            s = fmaf(a, sg, base);
            v[j] = d * s;
        }
        // 16 independent 64-lane butterflies (pipelined)
#pragma unroll
        for (int st = 1; st < 64; st <<= 1) {
#pragma unroll
            for (int j = 0; j < 16; ++j) v[j] += __shfl_xor(v[j], st, 64);
        }
        float out = v[0];
#pragma unroll
        for (int j = 1; j < 16; ++j) if (lane == j) out = v[j];
        if (lane < 16) red[w][lane] = out;
        __syncthreads();
        if (tid < 16) {
            float s4 = red[0][tid] + red[1][tid] + red[2][tid] + red[3][tid];
            partials[((size_t)(b * NBLK_N + nb)) * TT + tb + tid] = s4;
        }
        __syncthreads();
    }
}

// ---------------------------------------------------------------------------
// Finalize: m = (sum over blocks) / sum_density ; b_norm = 0.5*m + 0.5
// ---------------------------------------------------------------------------
__global__ __launch_bounds__(256) void finalize_kernel(
    const float* __restrict__ partials, const float* __restrict__ sum_ptr,
    float* __restrict__ out)
{
    int i = blockIdx.x * blockDim.x + threadIdx.x;
    if (i >= NB * TT) return;
    int b = i >> 11, t = i & (TT - 1);
    float acc = 0.f;
#pragma unroll 4
    for (int c = 0; c < NBLK_N; ++c)
        acc += partials[((size_t)(b * NBLK_N + c)) * TT + t];
    float m = acc / sum_ptr[0];
    out[OUT_M + i] = m;
    out[OUT_BNORM + i] = 0.5f * m + 0.5f;   // H_SCALE=0, M_SCALE=0.5, M_OFFSET=0.5
}

extern "C" void kernel_launch(void* const* d_in, const int* in_sizes, int n_in,
                              void* d_out, int out_size, void* d_ws, size_t ws_size,
                              hipStream_t stream) {
    // inputs: 0 encoder_input, 1 decoder_input, 2 initial_states, 3 y0,
    //         4 mesh, 5 W_in, 6 b_in, 7 W_blk, 8 b_blk, 9 W_out, 10 b_out
    const float* dec  = (const float*)d_in[1];
    const float* s0   = (const float*)d_in[2];
    const float* y0   = (const float*)d_in[3];
    const float* mesh = (const float*)d_in[4];
    const float* Win  = (const float*)d_in[5];
    const float* bin  = (const float*)d_in[6];
    const float* Wblk = (const float*)d_in[7];
    const float* bblk = (const float*)d_in[8];
    const float* Wout = (const float*)d_in[9];
    const float* bout = (const float*)d_in[10];
    float* out = (float*)d_out;
    float* ws  = (float*)d_ws;

    float* ws_density  = ws + WS_DENSITY;
    float* ws_sum      = ws + WS_SUM;
    float* ws_partials = ws + WS_PART;

    mlp_kernel<<<(N_MESH + 31) / 32, 256, 0, stream>>>(
        mesh, Win, bin, Wblk, bblk, Wout, bout, ws_density);
    sum_kernel<<<1, 256, 0, stream>>>(ws_density, ws_sum);
    {
        int total = NB * N_MESH * 4;  // 164832
        bcast_kernel<<<(total + 255) / 256, 256, 0, stream>>>(
            ws_density, s0, mesh, out);
    }
    scan_kernel<<<dim3(NBLK_N, NB), 256, 0, stream>>>(
        dec, s0, y0, mesh, ws_density, ws_partials);
    finalize_kernel<<<(NB * TT + 255) / 256, 256, 0, stream>>>(
        ws_partials, ws_sum, out);
}

// Round 2
// 204.965 us; speedup vs baseline: 1.4287x; 1.4287x over previous
//
#include <hip/hip_runtime.h>
#include <math.h>

#define N_MESH   5151
#define NB       8
#define TT       2048
#define HID      256
#define NLAYERS  3
#define INV_TEMP 1000.0f
#define NBLK_N   21            // ceil(5151/256)
#define NCHUNK   16
#define CHUNK    128           // TT / NCHUNK
#define NPAD     5376          // NBLK_N*256

// ws layout (floats)
#define WS_DENSITY 0           // 5151 used
#define WS_SUM     5184        // 1
#define WS_PART    6144        // NB * NBLK_N * TT = 344064 -> ends 350208
#define WS_P       350208      // NCHUNK*NB*NPAD = 688128 -> ends 1038336
#define WS_Q       1038336     // 688128 -> ends 1726464
#define WS_SSTART  1726464     // 688128 -> ends 2414592 (~9.7 MB)

// out layout (floats)
#define OUT_BNORM  0           // 16384
#define OUT_DENSB  16384       // 41208
#define OUT_M      57592       // 16384
#define OUT_S0     73976       // 41208
#define OUT_MESHB  115184      // 82416

__device__ __forceinline__ float sigmoid_fast(float x) {
    float e = __expf(-x);
    return __builtin_amdgcn_rcpf(1.0f + e);
}

// ---------------------------------------------------------------------------
// Density MLP: rows wave-private (row = rg + 4*j), zero barriers.
// ---------------------------------------------------------------------------
__global__ __launch_bounds__(256) void mlp_kernel(
    const float* __restrict__ mesh, const float* __restrict__ Win,
    const float* __restrict__ bin,  const float* __restrict__ Wblk,
    const float* __restrict__ bblk, const float* __restrict__ Wout,
    const float* __restrict__ bout, float* __restrict__ ws_density)
{
    __shared__ float hA[32 * HID];          // 32 KB
    const int tid = threadIdx.x;
    const int lane = tid & 63;
    const int rg   = tid >> 6;
    const int c0   = lane * 4;
    const int row0 = blockIdx.x * 32;

    float4 w0 = *(const float4*)&Win[0 * HID + c0];
    float4 w1 = *(const float4*)&Win[1 * HID + c0];
    float4 bi = *(const float4*)&bin[c0];
#pragma unroll
    for (int j = 0; j < 8; ++j) {
        int r = rg + 4 * j;
        int gr = row0 + r;
        float m0 = 0.f, m1 = 0.f;
        if (gr < N_MESH) { m0 = mesh[2 * gr]; m1 = mesh[2 * gr + 1]; }
        float4 h;
        h.x = fmaxf(fmaf(m0, w0.x, fmaf(m1, w1.x, bi.x)), 0.f);
        h.y = fmaxf(fmaf(m0, w0.y, fmaf(m1, w1.y, bi.y)), 0.f);
        h.z = fmaxf(fmaf(m0, w0.z, fmaf(m1, w1.z, bi.z)), 0.f);
        h.w = fmaxf(fmaf(m0, w0.w, fmaf(m1, w1.w, bi.w)), 0.f);
        *(float4*)&hA[r * HID + c0] = h;
    }

    for (int L = 0; L < NLAYERS; ++L) {
        const float* W = Wblk + (size_t)L * HID * HID;
        float acc[8][4];
#pragma unroll
        for (int j = 0; j < 8; ++j)
#pragma unroll
            for (int q = 0; q < 4; ++q) acc[j][q] = 0.f;

#pragma unroll 4
        for (int k = 0; k < HID; ++k) {
            float4 w = *(const float4*)&W[k * HID + c0];
#pragma unroll
            for (int j = 0; j < 8; ++j) {
                float hv = hA[(rg + 4 * j) * HID + k];
                acc[j][0] = fmaf(hv, w.x, acc[j][0]);
                acc[j][1] = fmaf(hv, w.y, acc[j][1]);
                acc[j][2] = fmaf(hv, w.z, acc[j][2]);
                acc[j][3] = fmaf(hv, w.w, acc[j][3]);
            }
        }
        float4 bb = *(const float4*)&bblk[L * HID + c0];
#pragma unroll
        for (int j = 0; j < 8; ++j) {
            int r = rg + 4 * j;
            float4 h = *(float4*)&hA[r * HID + c0];
            h.x += fmaxf(acc[j][0] + bb.x, 0.f);
            h.y += fmaxf(acc[j][1] + bb.y, 0.f);
            h.z += fmaxf(acc[j][2] + bb.z, 0.f);
            h.w += fmaxf(acc[j][3] + bb.w, 0.f);
            *(float4*)&hA[r * HID + c0] = h;
        }
    }

    float4 wo = *(const float4*)&Wout[c0];
    float bo = bout[0];
    float p[8];
#pragma unroll
    for (int j = 0; j < 8; ++j) {
        int r = rg + 4 * j;
        float4 h = *(float4*)&hA[r * HID + c0];
        p[j] = h.x * wo.x + h.y * wo.y + h.z * wo.z + h.w * wo.w;
    }
#pragma unroll
    for (int st = 1; st < 64; st <<= 1)
#pragma unroll
        for (int j = 0; j < 8; ++j) p[j] += __shfl_xor(p[j], st, 64);

    if (lane < 8) {
        float sel = p[0];
#pragma unroll
        for (int j = 1; j < 8; ++j) if (lane == j) sel = p[j];
        int gr = row0 + rg + 4 * lane;
        if (gr < N_MESH) ws_density[gr] = sigmoid_fast(sel + bo);
    }
}

__global__ __launch_bounds__(256) void sum_kernel(const float* __restrict__ density,
                                                  float* __restrict__ sum_out)
{
    __shared__ float red[4];
    float p = 0.f;
    for (int i = threadIdx.x; i < N_MESH; i += 256) p += density[i];
#pragma unroll
    for (int st = 1; st < 64; st <<= 1) p += __shfl_xor(p, st, 64);
    int lane = threadIdx.x & 63, w = threadIdx.x >> 6;
    if (lane == 0) red[w] = p;
    __syncthreads();
    if (threadIdx.x == 0) sum_out[0] = red[0] + red[1] + red[2] + red[3];
}

__global__ __launch_bounds__(256) void bcast_kernel(
    const float* __restrict__ density, const float* __restrict__ s0,
    const float* __restrict__ mesh, float* __restrict__ out)
{
    int i = blockIdx.x * blockDim.x + threadIdx.x;
    const int n1 = NB * N_MESH;
    const int n2 = 2 * n1;
    const int total = n2 + NB * N_MESH * 2;
    if (i >= total) return;
    if (i < n1) {
        out[OUT_DENSB + i] = density[i % N_MESH];
    } else if (i < n2) {
        int j = i - n1;
        out[OUT_S0 + j] = s0[j];
    } else {
        int j = i - n2;
        out[OUT_MESHB + j] = mesh[j % (2 * N_MESH)];
    }
}

// ---------------------------------------------------------------------------
// Phase 1: per (b,n,chunk) compose the affine map (P,Q) over CHUNK steps.
// s_t = A*s_{t-1} + B ; inc: A=1-up, B=up ; dec: A=dn, B=dn-1
// grid = (NBLK_N, NB, NCHUNK)
// ---------------------------------------------------------------------------
__global__ __launch_bounds__(256) void scan_phase1(
    const float* __restrict__ dec, const float* __restrict__ y0,
    const float* __restrict__ mesh, float* __restrict__ Pout,
    float* __restrict__ Qout)
{
    __shared__ float hs[CHUNK];
    const int tid = threadIdx.x;
    const int nb = blockIdx.x, b = blockIdx.y, c = blockIdx.z;
    const int n = nb * 256 + tid;
    const int t0 = c * CHUNK;

    if (tid < CHUNK) hs[tid] = dec[b * TT + t0 + tid];
    float alpha = 4.f, beta = 4.f;
    if (n < N_MESH) { beta = mesh[2 * n]; alpha = mesh[2 * n + 1]; }
    float hp = (c == 0) ? y0[b] : dec[b * TT + t0 - 1];
    __syncthreads();

    float P = 1.f, Q = 0.f;
#pragma unroll 8
    for (int j = 0; j < CHUNK; ++j) {
        float ht = hs[j];
        bool inc = (ht >= hp); hp = ht;
        float thr = inc ? alpha : beta;
        float e  = __expf((thr - ht) * INV_TEMP);
        float s1 = __builtin_amdgcn_rcpf(1.0f + e);   // sigmoid((ht-thr)/T)
        float A  = inc ? (1.0f - s1) : s1;
        float B  = inc ? s1 : (s1 - 1.0f);
        P = A * P;
        Q = fmaf(A, Q, B);
    }
    size_t idx = ((size_t)(c * NB + b)) * NPAD + n;
    Pout[idx] = P;
    Qout[idx] = Q;
}

// ---------------------------------------------------------------------------
// Phase 2: chunk-boundary states. grid = (NBLK_N, NB)
// ---------------------------------------------------------------------------
__global__ __launch_bounds__(256) void scan_phase2(
    const float* __restrict__ s0_in, const float* __restrict__ P,
    const float* __restrict__ Q, float* __restrict__ Sstart)
{
    const int tid = threadIdx.x;
    const int nb = blockIdx.x, b = blockIdx.y;
    const int n = nb * 256 + tid;
    float s = (n < N_MESH) ? s0_in[b * N_MESH + n] : 0.f;
#pragma unroll
    for (int c = 0; c < NCHUNK; ++c) {
        size_t idx = ((size_t)(c * NB + b)) * NPAD + n;
        Sstart[idx] = s;
        s = fmaf(P[idx], s, Q[idx]);
    }
}

// ---------------------------------------------------------------------------
// Phase 3: replay each chunk from its boundary state, reduce d*s over n.
// grid = (NBLK_N, NB, NCHUNK)
// ---------------------------------------------------------------------------
__global__ __launch_bounds__(256) void scan_phase3(
    const float* __restrict__ dec, const float* __restrict__ y0,
    const float* __restrict__ mesh, const float* __restrict__ density,
    const float* __restrict__ Sstart, float* __restrict__ partials)
{
    __shared__ float hs[CHUNK];
    __shared__ float red[4][16];
    const int tid = threadIdx.x;
    const int nb = blockIdx.x, b = blockIdx.y, c = blockIdx.z;
    const int n = nb * 256 + tid;
    const int lane = tid & 63, w = tid >> 6;
    const int t0 = c * CHUNK;

    if (tid < CHUNK) hs[tid] = dec[b * TT + t0 + tid];
    float alpha = 4.f, beta = 4.f, d = 0.f;
    if (n < N_MESH) { beta = mesh[2 * n]; alpha = mesh[2 * n + 1]; d = density[n]; }
    float s = Sstart[((size_t)(c * NB + b)) * NPAD + n];
    float hp = (c == 0) ? y0[b] : dec[b * TT + t0 - 1];
    __syncthreads();

    for (int tb = 0; tb < CHUNK; tb += 16) {
        float v[16];
#pragma unroll
        for (int j = 0; j < 16; ++j) {
            float ht = hs[tb + j];
            bool inc = (ht >= hp); hp = ht;
            float thr = inc ? alpha : beta;
            float e  = __expf((thr - ht) * INV_TEMP);
            float s1 = __builtin_amdgcn_rcpf(1.0f + e);
            float A  = inc ? (1.0f - s1) : s1;
            float B  = inc ? s1 : (s1 - 1.0f);
            s = fmaf(A, s, B);
            v[j] = d * s;
        }
#pragma unroll
        for (int st = 1; st < 64; st <<= 1) {
#pragma unroll
            for (int j = 0; j < 16; ++j) v[j] += __shfl_xor(v[j], st, 64);
        }
        float outv = v[0];
#pragma unroll
        for (int j = 1; j < 16; ++j) if (lane == j) outv = v[j];
        if (lane < 16) red[w][lane] = outv;
        __syncthreads();
        if (tid < 16) {
            float s4 = red[0][tid] + red[1][tid] + red[2][tid] + red[3][tid];
            partials[((size_t)(b * NBLK_N + nb)) * TT + t0 + tb + tid] = s4;
        }
        __syncthreads();
    }
}

__global__ __launch_bounds__(256) void finalize_kernel(
    const float* __restrict__ partials, const float* __restrict__ sum_ptr,
    float* __restrict__ out)
{
    int i = blockIdx.x * blockDim.x + threadIdx.x;
    if (i >= NB * TT) return;
    int b = i >> 11, t = i & (TT - 1);
    float acc = 0.f;
#pragma unroll 4
    for (int c = 0; c < NBLK_N; ++c)
        acc += partials[((size_t)(b * NBLK_N + c)) * TT + t];
    float m = acc / sum_ptr[0];
    out[OUT_M + i] = m;
    out[OUT_BNORM + i] = 0.5f * m + 0.5f;
}

extern "C" void kernel_launch(void* const* d_in, const int* in_sizes, int n_in,
                              void* d_out, int out_size, void* d_ws, size_t ws_size,
                              hipStream_t stream) {
    const float* dec  = (const float*)d_in[1];
    const float* s0   = (const float*)d_in[2];
    const float* y0   = (const float*)d_in[3];
    const float* mesh = (const float*)d_in[4];
    const float* Win  = (const float*)d_in[5];
    const float* bin  = (const float*)d_in[6];
    const float* Wblk = (const float*)d_in[7];
    const float* bblk = (const float*)d_in[8];
    const float* Wout = (const float*)d_in[9];
    const float* bout = (const float*)d_in[10];
    float* out = (float*)d_out;
    float* ws  = (float*)d_ws;

    float* ws_density  = ws + WS_DENSITY;
    float* ws_sum      = ws + WS_SUM;
    float* ws_partials = ws + WS_PART;
    float* ws_P        = ws + WS_P;
    float* ws_Q        = ws + WS_Q;
    float* ws_S        = ws + WS_SSTART;

    scan_phase1<<<dim3(NBLK_N, NB, NCHUNK), 256, 0, stream>>>(
        dec, y0, mesh, ws_P, ws_Q);
    mlp_kernel<<<(N_MESH + 31) / 32, 256, 0, stream>>>(
        mesh, Win, bin, Wblk, bblk, Wout, bout, ws_density);
    sum_kernel<<<1, 256, 0, stream>>>(ws_density, ws_sum);
    {
        int total = NB * N_MESH * 4;
        bcast_kernel<<<(total + 255) / 256, 256, 0, stream>>>(
            ws_density, s0, mesh, out);
    }
    scan_phase2<<<dim3(NBLK_N, NB), 256, 0, stream>>>(s0, ws_P, ws_Q, ws_S);
    scan_phase3<<<dim3(NBLK_N, NB, NCHUNK), 256, 0, stream>>>(
        dec, y0, mesh, ws_density, ws_S, ws_partials);
    finalize_kernel<<<(NB * TT + 255) / 256, 256, 0, stream>>>(
        ws_partials, ws_sum, out);
}